// Round 16
// baseline (703.327 us; speedup 1.0000x reference)
//
#include <hip/hip_runtime.h>
#include <hip/hip_bf16.h>

#define T_STEPS 512
#define BATCH   1024
#define HD1     80
#define HD2     100
#define NB2     16                     // batches per block (MFMA N=16)
#define NGRP    (BATCH / NB2)          // 64 batch groups

// ---- MFMA fragment geometry (unchanged) ----
#define NKT1    3
#define NUT1    5
#define NT1     (4 * NUT1)             // 20
#define NKT2    6
#define NUT2    7
#define NT2     (4 * NUT2)             // 28
#define W1F_DW  (NT1 * NKT1 * 64 * 4)  // 15360 dwords of lstm1 A-fragments
#define W2F_DW  (NT2 * NKT2 * 64 * 4)  // 43008 dwords of lstm2 A-fragments

// ---- chunked h1 handoff ----
#define CH      16                     // steps per chunk
#define NCH     (T_STEPS / CH)         // 32 chunks
#define LINE_H  1280                   // halfs per (t,g) h1 line: 10 groups x 16 x 8

typedef _Float16 half2_t __attribute__((ext_vector_type(2)));
typedef _Float16 f16x4   __attribute__((ext_vector_type(4)));
typedef _Float16 f16x8   __attribute__((ext_vector_type(8)));
typedef float    f32x4   __attribute__((ext_vector_type(4)));

union HU { unsigned int u; half2_t h; };
static __device__ __forceinline__ unsigned int packh(float a, float b) {
    HU x; x.h.x = (_Float16)a; x.h.y = (_Float16)b; return x.u;
}

// ---------------------------------------------------------------------------
// R16: gate evaluation with PAIR-BATCHED reciprocals — 5 exp + 2 rcp per
// unit (was 5 exp + 5 rcp). Exact algebra:
//   gf            = 1/(1+ef)
//   gi*tanh(zg)   = (1-eg) / [(1+ei)(1+eg)]
//   go*tanh(c)    = (1-ec) / [(1+eo)(1+ec)]
// One rcp of the product recovers both factors: inv=rcp(df*dig);
// gf=inv*dig; 1/dig=inv*df. Clamps (z>=-20) bound every product by
// e^80 << f32-max; beyond that the true gate is ~0 and inv->0 matches.
// Rationale: per-iter wall ~2600-2900cy was INVARIANT across R12-R15's
// structural changes; the invariant term is the 40 trans-ops/lane/iter on
// the narrow trans pipe (~8-16cy each, 2 worker waves/SIMD = 640-1280cy).
// This cuts it to 28/lane. VALU adds ~10 ops (cheap, 2cy).
// ---------------------------------------------------------------------------
static __device__ __forceinline__ float gates_update(
    float zi, float zf, float zg, float zo, float& c)
{
    float ei = __expf(-fmaxf(zi, -20.f));
    float ef = __expf(-fmaxf(zf, -20.f));
    float eg = __expf(-2.f * fmaxf(zg, -20.f));
    float eo = __expf(-fmaxf(zo, -20.f));
    float df   = 1.f + ef;
    float dig  = (1.f + ei) * (1.f + eg);
    float inv1 = __builtin_amdgcn_rcpf(df * dig);
    float gf   = inv1 * dig;                    // 1/df
    float gig  = (1.f - eg) * (inv1 * df);      // gi*tanh(zg)
    c = fmaf(gf, c, gig);
    float ec  = __expf(-2.f * fmaxf(c, -20.f));
    float doc = (1.f + eo) * (1.f + ec);
    return (1.f - ec) * __builtin_amdgcn_rcpf(doc);   // go*tanh(c)
}

static __device__ __forceinline__ void gld_lds16(const void* g, void* l) {
    __builtin_amdgcn_global_load_lds(
        (const __attribute__((address_space(1))) unsigned int*)g,
        (__attribute__((address_space(3))) unsigned int*)l, 16, 0, 0);
}

// ---------------------------------------------------------------------------
// Prep (unchanged) + flag zeroing.
// ---------------------------------------------------------------------------
__global__ __launch_bounds__(256)
void prep_kernel(const float* __restrict__ W_hh1,
                 const float* __restrict__ W_ih2,
                 const float* __restrict__ W_hh2,
                 const float* __restrict__ W_ih1,
                 const float* __restrict__ b_ih1,
                 const float* __restrict__ b_hh1,
                 const float* __restrict__ b_ih2,
                 const float* __restrict__ b_hh2,
                 unsigned int* __restrict__ w1f,
                 unsigned int* __restrict__ w2f,
                 int* __restrict__ flags)
{
    int i = blockIdx.x * 256 + threadIdx.x;
    if (i < W1F_DW) {
        int H  = 2 * i;
        int s  = H & 7;
        int l  = (H >> 3) & 63;
        int ri = H >> 9;
        int kt = ri % NKT1;
        int tile = ri / NKT1;
        int g  = tile / NUT1, j = tile % NUT1;
        int r  = g * HD1 + j * 16 + (l & 15);
        int k  = kt * 32 + (l >> 4) * 8 + s;
        auto val1 = [&](int kk) -> float {
            if (kk < HD1) return W_hh1[r * HD1 + kk];
            if (kk == HD1) return b_ih1[r] + b_hh1[r];
            if (kk == HD1 + 1) return W_ih1[r];
            return 0.f;
        };
        w1f[i] = packh(val1(k), val1(k + 1));
    } else if (i < W1F_DW + W2F_DW) {
        int d  = i - W1F_DW;
        int H  = 2 * d;
        int s  = H & 7;
        int l  = (H >> 3) & 63;
        int ri = H >> 9;
        int kt = ri % NKT2;
        int tile = ri / NKT2;
        int g  = tile / NUT2, j = tile % NUT2;
        int up = j * 16 + (l & 15);
        int k  = kt * 32 + (l >> 4) * 8 + s;
        float v0 = 0.f, v1 = 0.f;
        if (up < HD2) {
            int r = g * HD2 + up;
            auto val2 = [&](int kk) -> float {
                if (kk < HD1) return W_ih2[r * HD1 + kk];
                if (kk < HD1 + HD2) return W_hh2[r * HD2 + (kk - HD1)];
                if (kk == HD1 + HD2) return b_ih2[r] + b_hh2[r];
                return 0.f;
            };
            v0 = val2(k); v1 = val2(k + 1);
        }
        w2f[d] = packh(v0, v1);
    } else if (i < W1F_DW + W2F_DW + NGRP * NCH) {
        flags[i - W1F_DW - W2F_DW] = 0;
    }
}

// ---------------------------------------------------------------------------
// CONCURRENT LAYER-SPLIT two-layer LSTM. 128 blocks x 512 threads.
// Structure identical to R15 (passed); only the gate math changed (R16).
// ---------------------------------------------------------------------------
__global__ __launch_bounds__(512, 1)
void lstm_split(const float* __restrict__ x,
                const _Float16* __restrict__ w1f,
                const _Float16* __restrict__ w2f,
                _Float16* __restrict__ h1g,     // [NCH][NGRP][CH][LINE_H]
                int* __restrict__ flags,        // [NGRP][NCH]
                float* __restrict__ h2last)
{
    const int tid = threadIdx.x;
    const int l   = tid & 63;
    const int wv  = tid >> 6;              // 0..7
    const int bt  = l & 15;                // batch column (C/D col = lane&15)
    const int ro  = (l >> 4) << 2;         // unit offset  (C/D row)
    const int lane_base = ((l >> 4) << 7) + (bt << 3);

    __shared__ float    xs[T_STEPS * NB2];           // 32KB (producer)
    __shared__ _Float16 h1b[2][12 * 128];            // 6KB  (producer)
    __shared__ _Float16 chunkbuf[2][CH * LINE_H];    // 80KB (consumer)
    __shared__ _Float16 h2buf[2][14 * 128];          // 7KB  (consumer)

    if (blockIdx.x < NGRP) {
        // =================== PRODUCER: LSTM layer 1 =======================
        const int g  = blockIdx.x;
        const int b0 = g * NB2;
        const bool workerW = (wv < 5);
        const int u0 = wv * 16 + ro;

        f16x8 a[4][NKT1];
        if (workerW) {
#pragma unroll
            for (int gg = 0; gg < 4; gg++)
#pragma unroll
                for (int kt = 0; kt < NKT1; kt++)
                    a[gg][kt] = *(const volatile f16x8*)(w1f +
                        ((size_t)((gg * NUT1 + wv) * NKT1 + kt) * 64 + l) * 8);
        }
        float c[4] = {0.f, 0.f, 0.f, 0.f};

        for (int i = tid; i < 2 * 12 * 128 / 2; i += 512) ((unsigned int*)h1b)[i] = 0u;
        for (int idx = tid; idx < T_STEPS * NB2; idx += 512) {
            int tt = idx & (T_STEPS - 1), bb = idx >> 9;
            xs[tt * NB2 + bb] = x[((size_t)(b0 + bb)) * T_STEPS + tt];
        }
        __syncthreads();
        if (tid < NB2) {
            h1b[0][10 * 128 + tid * 8 + 0] = (_Float16)1.f;
            h1b[1][10 * 128 + tid * 8 + 0] = (_Float16)1.f;
            h1b[1][10 * 128 + tid * 8 + 1] = (_Float16)xs[0 * NB2 + tid];
        }
        __syncthreads();

#pragma unroll 2
        for (int i = 0; i < T_STEPS; i++) {
            const int rp = (i - 1) & 1, wp = i & 1;
            if (workerW) {
                const _Float16* bp = &h1b[rp][0] + lane_base;
                f16x8 bfr[NKT1];
#pragma unroll
                for (int kt = 0; kt < NKT1; kt++)
                    bfr[kt] = *(const f16x8*)(bp + kt * 512);
                f32x4 acc[4];
#pragma unroll
                for (int gg = 0; gg < 4; gg++) {
                    f32x4 z4 = {0.f, 0.f, 0.f, 0.f};
#pragma unroll
                    for (int kt = 0; kt < NKT1; kt++)
                        z4 = __builtin_amdgcn_mfma_f32_16x16x32_f16(
                                 a[gg][kt], bfr[kt], z4, 0, 0, 0);
                    acc[gg] = z4;
                }
                f16x4 hraw, hrel;
#pragma unroll
                for (int r = 0; r < 4; r++) {
                    float h = gates_update(acc[0][r], acc[1][r],
                                           acc[2][r], acc[3][r], c[r]);
                    hraw[r] = (_Float16)h;
                    hrel[r] = (_Float16)fmaxf(h, 0.f);
                }
                int off = (u0 >> 3) * 128 + (bt << 3) + (u0 & 7);
                *(f16x4*)&h1b[wp][off] = hraw;
                size_t goff = (((size_t)(i >> 4) * NGRP + g) * CH + (i & 15)) * LINE_H + off;
                *(f16x4*)(h1g + goff) = hrel;     // stays in flight (no per-iter drain)
            } else if (wv == 5 && l < NB2 && i + 1 < T_STEPS) {
                h1b[wp][10 * 128 + l * 8 + 1] = (_Float16)xs[(i + 1) * NB2 + l];
            }
            // per-iter barrier drains LDS only; vmcnt only at chunk end.
            if ((i & 15) == 15) {
                asm volatile("s_waitcnt vmcnt(0) lgkmcnt(0)" ::: "memory");
                __builtin_amdgcn_s_barrier();
                if (tid == 0) {
                    __threadfence();
                    __hip_atomic_store(&flags[g * NCH + (i >> 4)], 1,
                                       __ATOMIC_RELEASE, __HIP_MEMORY_SCOPE_AGENT);
                }
            } else {
                asm volatile("s_waitcnt lgkmcnt(0)" ::: "memory");
                __builtin_amdgcn_s_barrier();
            }
        }
    } else {
        // =================== CONSUMER: LSTM layer 2 =======================
        const int g  = blockIdx.x - NGRP;
        const int b0 = g * NB2;
        const bool workerWave = (wv < 7);
        const int u0 = wv * 16 + ro;
        const bool worker = workerWave && (u0 < HD2);
        const bool k2low = ((l >> 4) < 2);     // kt=2 fragment: h1 vs h2 half

        f16x8 a[4][NKT2];
        if (workerWave) {
#pragma unroll
            for (int gg = 0; gg < 4; gg++)
#pragma unroll
                for (int kt = 0; kt < NKT2; kt++)
                    a[gg][kt] = *(const volatile f16x8*)(w2f +
                        ((size_t)((gg * NUT2 + wv) * NKT2 + kt) * 64 + l) * 8);
        }
        float c[4] = {0.f, 0.f, 0.f, 0.f};

        for (int i = tid; i < 2 * 14 * 128 / 2; i += 512) ((unsigned int*)h2buf)[i] = 0u;
        __syncthreads();
        if (tid < NB2) {
            h2buf[0][12 * 128 + tid * 8 + 4] = (_Float16)1.f;   // k=180: 1.0
            h2buf[1][12 * 128 + tid * 8 + 4] = (_Float16)1.f;
        }
        if (wv == 7) {
            while (__hip_atomic_load(&flags[g * NCH], __ATOMIC_ACQUIRE,
                                     __HIP_MEMORY_SCOPE_AGENT) == 0)
                __builtin_amdgcn_s_sleep(8);
            const _Float16* gsrc = h1g + (size_t)g * (CH * LINE_H) + l * 8;
#pragma unroll
            for (int q = 0; q < 40; q++)
                gld_lds16(gsrc + q * 512, &chunkbuf[0][q * 512]);
        }
        __syncthreads();                   // uniform site: drains prologue DMA

        int cb = 0;
        bool nissued = false;
        for (int i = 0; i < T_STEPS; i++) {
            const int tc = i & (CH - 1);
            const int ch = i >> 4;
            if (workerWave) {
                // ---- [A] pre-barrier: h1-only frags + 8 MFMA (stable) ----
                const _Float16* ck = &chunkbuf[cb][tc * LINE_H];
                f16x8 b0f = *(const f16x8*)(ck + lane_base);
                f16x8 b1f = *(const f16x8*)(ck + lane_base + 512);
                f32x4 pa[4];
#pragma unroll
                for (int gg = 0; gg < 4; gg++) {
                    f32x4 z4 = {0.f, 0.f, 0.f, 0.f};
                    z4 = __builtin_amdgcn_mfma_f32_16x16x32_f16(a[gg][0], b0f, z4, 0, 0, 0);
                    pa[gg] = __builtin_amdgcn_mfma_f32_16x16x32_f16(a[gg][1], b1f, z4, 0, 0, 0);
                }
                __syncthreads();           // h2(i-1) visible; chunk drained at boundary
                // ---- [C] h2-dependent frags (kt=2 mixed, kt=3..5 uniform) ----
                const _Float16* h2p = &h2buf[i & 1][0];
                f16x8 b2f = k2low ? *(const f16x8*)(ck  + lane_base + 1024)
                                  : *(const f16x8*)(h2p + lane_base - 256);
                f16x8 b3f = *(const f16x8*)(h2p + lane_base + 256);
                f16x8 b4f = *(const f16x8*)(h2p + lane_base + 768);
                f16x8 b5f = *(const f16x8*)(h2p + lane_base + 1280);
                // ---- [D] 16 MFMA, split chains (post-barrier depth 2) ----
                f32x4 acc[4];
#pragma unroll
                for (int gg = 0; gg < 4; gg++) {
                    f32x4 cA = __builtin_amdgcn_mfma_f32_16x16x32_f16(a[gg][2], b2f, pa[gg], 0, 0, 0);
                    cA = __builtin_amdgcn_mfma_f32_16x16x32_f16(a[gg][3], b3f, cA, 0, 0, 0);
                    f32x4 cB = {0.f, 0.f, 0.f, 0.f};
                    cB = __builtin_amdgcn_mfma_f32_16x16x32_f16(a[gg][4], b4f, cB, 0, 0, 0);
                    cB = __builtin_amdgcn_mfma_f32_16x16x32_f16(a[gg][5], b5f, cB, 0, 0, 0);
                    acc[gg] = cA + cB;
                }
                // ---- [E] gates, c, h ----
                if (worker) {
                    f16x4 hh;
#pragma unroll
                    for (int r = 0; r < 4; r++) {
                        float h = gates_update(acc[0][r], acc[1][r],
                                               acc[2][r], acc[3][r], c[r]);
                        hh[r] = (_Float16)h;
                        if (i == T_STEPS - 1)
                            h2last[(size_t)(b0 + bt) * HD2 + u0 + r] = fmaxf(h, 0.f);
                    }
                    int k0 = HD1 + u0;
                    *(f16x4*)&h2buf[(i + 1) & 1]
                        [((k0 >> 3) - 10) * 128 + (bt << 3) + (k0 & 7)] = hh;
                }
            } else {
                // ---- stager: issue DMA early; counted drain at tc==15 ----
                if (!nissued && ch + 1 < NCH) {
                    bool rdy = (__hip_atomic_load(&flags[g * NCH + ch + 1],
                                    __ATOMIC_ACQUIRE, __HIP_MEMORY_SCOPE_AGENT) != 0);
                    if (tc == CH - 1 && !rdy) {
                        while (__hip_atomic_load(&flags[g * NCH + ch + 1],
                                   __ATOMIC_ACQUIRE, __HIP_MEMORY_SCOPE_AGENT) == 0)
                            __builtin_amdgcn_s_sleep(8);
                        rdy = true;
                    }
                    if (rdy) {
                        const _Float16* gsrc = h1g +
                            ((size_t)(ch + 1) * NGRP + g) * (CH * LINE_H) + l * 8;
                        _Float16* dst = &chunkbuf[cb ^ 1][0];
#pragma unroll
                        for (int q = 0; q < 40; q++)
                            gld_lds16(gsrc + q * 512, dst + q * 512);
                        nissued = true;
                    }
                }
                if (tc == CH - 1)
                    asm volatile("s_waitcnt vmcnt(0)" ::: "memory");
                __builtin_amdgcn_s_barrier();   // pairs with workers' __syncthreads
            }
            if (tc == CH - 1) { cb ^= 1; nissued = false; }
        }
    }
}

// ---------------------------------------------------------------------------
// Head: out[b] = W_l2 @ relu(W_l1 @ h2last[b] + b_l1) + b_l2
// ---------------------------------------------------------------------------
__global__ __launch_bounds__(64)
void head_kernel(const float* __restrict__ h2last,
                 const float* __restrict__ W_l1,
                 const float* __restrict__ b_l1,
                 const float* __restrict__ W_l2,
                 const float* __restrict__ b_l2,
                 float* __restrict__ out)
{
    int b = blockIdx.x * 64 + threadIdx.x;
    if (b >= BATCH) return;
    const float* h = h2last + (size_t)b * HD2;
    float o = b_l2[0];
#pragma unroll
    for (int u = 0; u < 10; u++) {
        float s = b_l1[u];
#pragma unroll
        for (int k = 0; k < HD2; k++) s = fmaf(W_l1[u * HD2 + k], h[k], s);
        o = fmaf(W_l2[u], fmaxf(s, 0.f), o);
    }
    out[b] = o;
}

extern "C" void kernel_launch(void* const* d_in, const int* in_sizes, int n_in,
                              void* d_out, int out_size, void* d_ws, size_t ws_size,
                              hipStream_t stream)
{
    const float* x     = (const float*)d_in[0];
    const float* W_ih1 = (const float*)d_in[1];
    const float* W_hh1 = (const float*)d_in[2];
    const float* b_ih1 = (const float*)d_in[3];
    const float* b_hh1 = (const float*)d_in[4];
    const float* W_ih2 = (const float*)d_in[5];
    const float* W_hh2 = (const float*)d_in[6];
    const float* b_ih2 = (const float*)d_in[7];
    const float* b_hh2 = (const float*)d_in[8];
    const float* W_l1  = (const float*)d_in[9];
    const float* b_l1  = (const float*)d_in[10];
    const float* W_l2  = (const float*)d_in[11];
    const float* b_l2  = (const float*)d_in[12];
    float* out = (float*)d_out;

    // ws layout: h2last f32 | w1f | w2f | flags | h1g chunks (84 MB)
    char* p = (char*)d_ws;
    float* h2last      = (float*)p;        p += (size_t)BATCH * HD2 * 4;
    unsigned int* w1fu = (unsigned int*)p; p += (size_t)W1F_DW * 4;
    unsigned int* w2fu = (unsigned int*)p; p += (size_t)W2F_DW * 4;
    int* flags         = (int*)p;          p += (size_t)NGRP * NCH * 4;
    _Float16* h1g      = (_Float16*)p;

    int prep_n = W1F_DW + W2F_DW + NGRP * NCH;
    hipLaunchKernelGGL(prep_kernel, dim3((prep_n + 255) / 256), dim3(256), 0, stream,
                       W_hh1, W_ih2, W_hh2, W_ih1, b_ih1, b_hh1, b_ih2, b_hh2,
                       w1fu, w2fu, flags);
    hipLaunchKernelGGL(lstm_split, dim3(2 * NGRP), dim3(512), 0, stream,
                       x, (const _Float16*)w1fu, (const _Float16*)w2fu,
                       h1g, flags, h2last);
    hipLaunchKernelGGL(head_kernel, dim3(BATCH / 64), dim3(64), 0, stream,
                       h2last, W_l1, b_l1, W_l2, b_l2, out);
}

// Round 17
// 640.909 us; speedup vs baseline: 1.0974x; 1.0974x over previous
//
#include <hip/hip_runtime.h>
#include <hip/hip_bf16.h>

#define T_STEPS 512
#define BATCH   1024
#define HD1     80
#define HD2     100
#define NB2     16                     // batches per block (MFMA N=16)
#define NGRP    (BATCH / NB2)          // 64 batch groups

// ---- MFMA fragment geometry ----
#define NKT1    3
#define NUT1    5
#define NT1     (4 * NUT1)             // 20
#define NKT2    6
#define NUT2    7
#define NT2     (4 * NUT2)             // 28
#define W1F_DW  (NT1 * NKT1 * 64 * 4)  // 15360 dwords of lstm1 A-fragments
#define W2F_DW  (NT2 * NKT2 * 64 * 4)  // 43008 dwords of lstm2 A-fragments

// ---- chunked h1 handoff ----
#define CH      16                     // steps per chunk
#define NCH     (T_STEPS / CH)         // 32 chunks
#define LINE_H  1280                   // halfs per (t,g) h1 line: 10 groups x 16 x 8

typedef _Float16 half2_t __attribute__((ext_vector_type(2)));
typedef _Float16 f16x4   __attribute__((ext_vector_type(4)));
typedef _Float16 f16x8   __attribute__((ext_vector_type(8)));
typedef float    f32x4   __attribute__((ext_vector_type(4)));

union HU { unsigned int u; half2_t h; };
static __device__ __forceinline__ unsigned int packh(float a, float b) {
    HU x; x.h.x = (_Float16)a; x.h.y = (_Float16)b; return x.u;
}

// R17: reverted to R13's independent-rcp gates — R16's pair-batched form
// lengthened the dependent chain (mul->rcp->mul) and regressed 8% on this
// latency-bound recurrence. Chain length > op count here.
static __device__ __forceinline__ float sigm(float z) {
    return __builtin_amdgcn_rcpf(1.f + __expf(-z));
}
static __device__ __forceinline__ float tanhf_(float z) {
    return fmaf(2.f, __builtin_amdgcn_rcpf(1.f + __expf(-2.f * z)), -1.f);
}

static __device__ __forceinline__ void gld_lds16(const void* g, void* l) {
    __builtin_amdgcn_global_load_lds(
        (const __attribute__((address_space(1))) unsigned int*)g,
        (__attribute__((address_space(3))) unsigned int*)l, 16, 0, 0);
}

// ---------------------------------------------------------------------------
// Prep + flag zeroing (unchanged).
// ---------------------------------------------------------------------------
__global__ __launch_bounds__(256)
void prep_kernel(const float* __restrict__ W_hh1,
                 const float* __restrict__ W_ih2,
                 const float* __restrict__ W_hh2,
                 const float* __restrict__ W_ih1,
                 const float* __restrict__ b_ih1,
                 const float* __restrict__ b_hh1,
                 const float* __restrict__ b_ih2,
                 const float* __restrict__ b_hh2,
                 unsigned int* __restrict__ w1f,
                 unsigned int* __restrict__ w2f,
                 int* __restrict__ flags)
{
    int i = blockIdx.x * 256 + threadIdx.x;
    if (i < W1F_DW) {
        int H  = 2 * i;
        int s  = H & 7;
        int l  = (H >> 3) & 63;
        int ri = H >> 9;
        int kt = ri % NKT1;
        int tile = ri / NKT1;
        int g  = tile / NUT1, j = tile % NUT1;
        int r  = g * HD1 + j * 16 + (l & 15);
        int k  = kt * 32 + (l >> 4) * 8 + s;
        auto val1 = [&](int kk) -> float {
            if (kk < HD1) return W_hh1[r * HD1 + kk];
            if (kk == HD1) return b_ih1[r] + b_hh1[r];
            if (kk == HD1 + 1) return W_ih1[r];
            return 0.f;
        };
        w1f[i] = packh(val1(k), val1(k + 1));
    } else if (i < W1F_DW + W2F_DW) {
        int d  = i - W1F_DW;
        int H  = 2 * d;
        int s  = H & 7;
        int l  = (H >> 3) & 63;
        int ri = H >> 9;
        int kt = ri % NKT2;
        int tile = ri / NKT2;
        int g  = tile / NUT2, j = tile % NUT2;
        int up = j * 16 + (l & 15);
        int k  = kt * 32 + (l >> 4) * 8 + s;
        float v0 = 0.f, v1 = 0.f;
        if (up < HD2) {
            int r = g * HD2 + up;
            auto val2 = [&](int kk) -> float {
                if (kk < HD1) return W_ih2[r * HD1 + kk];
                if (kk < HD1 + HD2) return W_hh2[r * HD2 + (kk - HD1)];
                if (kk == HD1 + HD2) return b_ih2[r] + b_hh2[r];
                return 0.f;
            };
            v0 = val2(k); v1 = val2(k + 1);
        }
        w2f[d] = packh(v0, v1);
    } else if (i < W1F_DW + W2F_DW + NGRP * NCH) {
        flags[i - W1F_DW - W2F_DW] = 0;
    }
}

// ---------------------------------------------------------------------------
// CONCURRENT LAYER-SPLIT two-layer LSTM. 128 blocks x 512 threads.
//
// R17: REVERT to R13 (best measured: 566us dispatch / 639.7us total).
// R14 (consumer chain cuts), R15 (producer store-drain diet), R16 (trans
// diet) were all noise-level or regressions — seven falsified mechanisms
// later, the per-iter floor is the barrier + inter-wave LDS round-trip that
// the recurrence structurally requires (every wave needs every other
// wave's h-slice each step), likely DVFS-deflated.
// ONE remaining probe vs R13: the stager polled the cross-XCD flag with a
// global acquire load EVERY iter until the next chunk was issued; in steady
// state the flag isn't ready until tc~15, so ~8-15 polls/chunk are wasted
// ~300-900cy round-trips that can delay the stager's barrier arrival (and
// thus all 8 waves). Poll only from tc>=8 (8 iters of DMA overlap remain;
// blocking at tc==15 unchanged -> same correctness).
// ---------------------------------------------------------------------------
__global__ __launch_bounds__(512, 1)
void lstm_split(const float* __restrict__ x,
                const _Float16* __restrict__ w1f,
                const _Float16* __restrict__ w2f,
                _Float16* __restrict__ h1g,     // [NCH][NGRP][CH][LINE_H]
                int* __restrict__ flags,        // [NGRP][NCH]
                float* __restrict__ h2last)
{
    const int tid = threadIdx.x;
    const int l   = tid & 63;
    const int wv  = tid >> 6;              // 0..7
    const int bt  = l & 15;                // batch column (C/D col = lane&15)
    const int ro  = (l >> 4) << 2;         // unit offset  (C/D row)
    const int lane_base = ((l >> 4) << 7) + (bt << 3);

    __shared__ float    xs[T_STEPS * NB2];           // 32KB (producer)
    __shared__ _Float16 h1b[2][12 * 128];            // 6KB  (producer)
    __shared__ _Float16 chunkbuf[2][CH * LINE_H];    // 80KB (consumer)
    __shared__ _Float16 h2buf[2][14 * 128];          // 7KB  (consumer)

    if (blockIdx.x < NGRP) {
        // =================== PRODUCER: LSTM layer 1 (R13 verbatim) ========
        const int g  = blockIdx.x;
        const int b0 = g * NB2;
        const bool workerW = (wv < 5);
        const int u0 = wv * 16 + ro;

        f16x8 a[4][NKT1];
        if (workerW) {
#pragma unroll
            for (int gg = 0; gg < 4; gg++)
#pragma unroll
                for (int kt = 0; kt < NKT1; kt++)
                    a[gg][kt] = *(const volatile f16x8*)(w1f +
                        ((size_t)((gg * NUT1 + wv) * NKT1 + kt) * 64 + l) * 8);
        }
        float c[4] = {0.f, 0.f, 0.f, 0.f};

        for (int i = tid; i < 2 * 12 * 128 / 2; i += 512) ((unsigned int*)h1b)[i] = 0u;
        for (int idx = tid; idx < T_STEPS * NB2; idx += 512) {
            int tt = idx & (T_STEPS - 1), bb = idx >> 9;
            xs[tt * NB2 + bb] = x[((size_t)(b0 + bb)) * T_STEPS + tt];
        }
        __syncthreads();
        if (tid < NB2) {
            h1b[0][10 * 128 + tid * 8 + 0] = (_Float16)1.f;
            h1b[1][10 * 128 + tid * 8 + 0] = (_Float16)1.f;
            h1b[1][10 * 128 + tid * 8 + 1] = (_Float16)xs[0 * NB2 + tid];
        }
        __syncthreads();

#pragma unroll 2
        for (int i = 0; i < T_STEPS; i++) {
            const int rp = (i - 1) & 1, wp = i & 1;
            if (workerW) {
                const _Float16* bp = &h1b[rp][0] + lane_base;
                f16x8 bfr[NKT1];
#pragma unroll
                for (int kt = 0; kt < NKT1; kt++)
                    bfr[kt] = *(const f16x8*)(bp + kt * 512);
                f32x4 acc[4];
#pragma unroll
                for (int gg = 0; gg < 4; gg++) {
                    f32x4 z4 = {0.f, 0.f, 0.f, 0.f};
#pragma unroll
                    for (int kt = 0; kt < NKT1; kt++)
                        z4 = __builtin_amdgcn_mfma_f32_16x16x32_f16(
                                 a[gg][kt], bfr[kt], z4, 0, 0, 0);
                    acc[gg] = z4;
                }
                f16x4 hraw, hrel;
#pragma unroll
                for (int r = 0; r < 4; r++) {
                    float gi = sigm(acc[0][r]);
                    float gf = sigm(acc[1][r]);
                    float gg2 = tanhf_(acc[2][r]);
                    float go = sigm(acc[3][r]);
                    c[r] = fmaf(gf, c[r], gi * gg2);
                    float h = go * tanhf_(c[r]);
                    hraw[r] = (_Float16)h;
                    hrel[r] = (_Float16)fmaxf(h, 0.f);
                }
                int off = (u0 >> 3) * 128 + (bt << 3) + (u0 & 7);
                *(f16x4*)&h1b[wp][off] = hraw;
                size_t goff = (((size_t)(i >> 4) * NGRP + g) * CH + (i & 15)) * LINE_H + off;
                *(f16x4*)(h1g + goff) = hrel;
            } else if (wv == 5 && l < NB2 && i + 1 < T_STEPS) {
                h1b[wp][10 * 128 + l * 8 + 1] = (_Float16)xs[(i + 1) * NB2 + l];
            }
            __syncthreads();               // drains chunk writes (vmcnt0)
            if ((i & 15) == 15 && tid == 0) {
                __threadfence();           // device-scope release of data
                __hip_atomic_store(&flags[g * NCH + (i >> 4)], 1,
                                   __ATOMIC_RELEASE, __HIP_MEMORY_SCOPE_AGENT);
            }
        }
    } else {
        // =================== CONSUMER: LSTM layer 2 (R13 + poll gate) =====
        const int g  = blockIdx.x - NGRP;
        const int b0 = g * NB2;
        const bool workerWave = (wv < 7);
        const int u0 = wv * 16 + ro;
        const bool worker = workerWave && (u0 < HD2);

        f16x8 a[4][NKT2];
        if (workerWave) {
#pragma unroll
            for (int gg = 0; gg < 4; gg++)
#pragma unroll
                for (int kt = 0; kt < NKT2; kt++)
                    a[gg][kt] = *(const volatile f16x8*)(w2f +
                        ((size_t)((gg * NUT2 + wv) * NKT2 + kt) * 64 + l) * 8);
        }
        float c[4] = {0.f, 0.f, 0.f, 0.f};

        for (int i = tid; i < 2 * 14 * 128 / 2; i += 512) ((unsigned int*)h2buf)[i] = 0u;
        __syncthreads();
        if (tid < NB2) {
            h2buf[0][12 * 128 + tid * 8 + 4] = (_Float16)1.f;   // k=180: 1.0
            h2buf[1][12 * 128 + tid * 8 + 4] = (_Float16)1.f;
        }
        // prologue: wait for chunk 0, DMA it
        if (wv == 7) {
            while (__hip_atomic_load(&flags[g * NCH], __ATOMIC_ACQUIRE,
                                     __HIP_MEMORY_SCOPE_AGENT) == 0)
                __builtin_amdgcn_s_sleep(8);
            const _Float16* gsrc = h1g + (size_t)g * (CH * LINE_H) + l * 8;
#pragma unroll
            for (int q = 0; q < 40; q++)
                gld_lds16(gsrc + q * 512, &chunkbuf[0][q * 512]);
        }
        __syncthreads();                   // drains DMA; bias slots visible

        int cb = 0;
        bool nissued = false;
        for (int i = 0; i < T_STEPS; i++) {
            const int tc = i & (CH - 1);
            const int ch = i >> 4;
            if (workerWave) {
                const _Float16* ck  = &chunkbuf[cb][tc * LINE_H];
                const _Float16* h2p = &h2buf[i & 1][0];
                f16x8 bfr[NKT2];
#pragma unroll
                for (int kt = 0; kt < NKT2; kt++) {
                    int gi = kt * 4 + (l >> 4);
                    const _Float16* src = (gi < 10)
                        ? (ck + gi * 128 + (bt << 3))
                        : (h2p + (gi - 10) * 128 + (bt << 3));
                    bfr[kt] = *(const f16x8*)src;
                }
                f32x4 acc[4];
#pragma unroll
                for (int gg = 0; gg < 4; gg++) {
                    f32x4 z4 = {0.f, 0.f, 0.f, 0.f};
#pragma unroll
                    for (int kt = 0; kt < NKT2; kt++)
                        z4 = __builtin_amdgcn_mfma_f32_16x16x32_f16(
                                 a[gg][kt], bfr[kt], z4, 0, 0, 0);
                    acc[gg] = z4;
                }
                if (worker) {
                    f16x4 hh;
#pragma unroll
                    for (int r = 0; r < 4; r++) {
                        float gi = sigm(acc[0][r]);
                        float gf = sigm(acc[1][r]);
                        float gg2 = tanhf_(acc[2][r]);
                        float go = sigm(acc[3][r]);
                        c[r] = fmaf(gf, c[r], gi * gg2);
                        float h = go * tanhf_(c[r]);
                        hh[r] = (_Float16)h;
                        if (i == T_STEPS - 1)
                            h2last[(size_t)(b0 + bt) * HD2 + u0 + r] = fmaxf(h, 0.f);
                    }
                    int k0 = HD1 + u0;
                    *(f16x4*)&h2buf[(i + 1) & 1]
                        [((k0 >> 3) - 10) * 128 + (bt << 3) + (k0 & 7)] = hh;
                }
            } else {
                // stager wave 7: poll only in the back half of the chunk
                // (R17: removes ~8 wasted cross-XCD acquire loads per chunk
                // from the barrier-coupled path; blocking at tc==15 intact)
                if (!nissued && ch + 1 < NCH && tc >= CH / 2) {
                    bool rdy = (__hip_atomic_load(&flags[g * NCH + ch + 1],
                                    __ATOMIC_ACQUIRE, __HIP_MEMORY_SCOPE_AGENT) != 0);
                    if (tc == CH - 1 && !rdy) {
                        while (__hip_atomic_load(&flags[g * NCH + ch + 1],
                                   __ATOMIC_ACQUIRE, __HIP_MEMORY_SCOPE_AGENT) == 0)
                            __builtin_amdgcn_s_sleep(8);
                        rdy = true;
                    }
                    if (rdy) {
                        const _Float16* gsrc = h1g +
                            ((size_t)(ch + 1) * NGRP + g) * (CH * LINE_H) + l * 8;
                        _Float16* dst = &chunkbuf[cb ^ 1][0];
#pragma unroll
                        for (int q = 0; q < 40; q++)
                            gld_lds16(gsrc + q * 512, dst + q * 512);
                        nissued = true;
                    }
                }
            }
            __syncthreads();               // single barrier/iter; drains stager DMA
            if (tc == CH - 1) { cb ^= 1; nissued = false; }
        }
    }
}

// ---------------------------------------------------------------------------
// Head: out[b] = W_l2 @ relu(W_l1 @ h2last[b] + b_l1) + b_l2
// ---------------------------------------------------------------------------
__global__ __launch_bounds__(64)
void head_kernel(const float* __restrict__ h2last,
                 const float* __restrict__ W_l1,
                 const float* __restrict__ b_l1,
                 const float* __restrict__ W_l2,
                 const float* __restrict__ b_l2,
                 float* __restrict__ out)
{
    int b = blockIdx.x * 64 + threadIdx.x;
    if (b >= BATCH) return;
    const float* h = h2last + (size_t)b * HD2;
    float o = b_l2[0];
#pragma unroll
    for (int u = 0; u < 10; u++) {
        float s = b_l1[u];
#pragma unroll
        for (int k = 0; k < HD2; k++) s = fmaf(W_l1[u * HD2 + k], h[k], s);
        o = fmaf(W_l2[u], fmaxf(s, 0.f), o);
    }
    out[b] = o;
}

extern "C" void kernel_launch(void* const* d_in, const int* in_sizes, int n_in,
                              void* d_out, int out_size, void* d_ws, size_t ws_size,
                              hipStream_t stream)
{
    const float* x     = (const float*)d_in[0];
    const float* W_ih1 = (const float*)d_in[1];
    const float* W_hh1 = (const float*)d_in[2];
    const float* b_ih1 = (const float*)d_in[3];
    const float* b_hh1 = (const float*)d_in[4];
    const float* W_ih2 = (const float*)d_in[5];
    const float* W_hh2 = (const float*)d_in[6];
    const float* b_ih2 = (const float*)d_in[7];
    const float* b_hh2 = (const float*)d_in[8];
    const float* W_l1  = (const float*)d_in[9];
    const float* b_l1  = (const float*)d_in[10];
    const float* W_l2  = (const float*)d_in[11];
    const float* b_l2  = (const float*)d_in[12];
    float* out = (float*)d_out;

    // ws layout: h2last f32 | w1f | w2f | flags | h1g chunks (84 MB)
    char* p = (char*)d_ws;
    float* h2last      = (float*)p;        p += (size_t)BATCH * HD2 * 4;
    unsigned int* w1fu = (unsigned int*)p; p += (size_t)W1F_DW * 4;
    unsigned int* w2fu = (unsigned int*)p; p += (size_t)W2F_DW * 4;
    int* flags         = (int*)p;          p += (size_t)NGRP * NCH * 4;
    _Float16* h1g      = (_Float16*)p;

    int prep_n = W1F_DW + W2F_DW + NGRP * NCH;
    hipLaunchKernelGGL(prep_kernel, dim3((prep_n + 255) / 256), dim3(256), 0, stream,
                       W_hh1, W_ih2, W_hh2, W_ih1, b_ih1, b_hh1, b_ih2, b_hh2,
                       w1fu, w2fu, flags);
    hipLaunchKernelGGL(lstm_split, dim3(2 * NGRP), dim3(512), 0, stream,
                       x, (const _Float16*)w1fu, (const _Float16*)w2fu,
                       h1g, flags, h2last);
    hipLaunchKernelGGL(head_kernel, dim3(BATCH / 64), dim3(64), 0, stream,
                       h2last, W_l1, b_l1, W_l2, b_l2, out);
}